// Round 5
// baseline (3505.383 us; speedup 1.0000x reference)
//
#include <hip/hip_runtime.h>
#include <stdint.h>

#define LY 6
#define VOC 512
#define DM 768
#define NH 12
#define HD 64
#define FFD 3072
#define BB 8
#define TT 1024
#define ROWS (BB*TT)

typedef short bf16x8 __attribute__((ext_vector_type(8)));
typedef float f32x4 __attribute__((ext_vector_type(4)));
typedef unsigned short u16x4 __attribute__((ext_vector_type(4)));

#if __has_builtin(__builtin_amdgcn_exp2f)
#define EXP2 __builtin_amdgcn_exp2f
#else
#define EXP2 exp2f
#endif

#if __has_builtin(__builtin_amdgcn_rcpf)
#define RCP __builtin_amdgcn_rcpf
#else
#define RCP(x) (1.0f/(x))
#endif

__device__ __forceinline__ unsigned short f2bf(float f) {
    union { float f; uint32_t u; } v; v.f = f;
    uint32_t r = v.u + 0x7FFFu + ((v.u >> 16) & 1u);
    return (unsigned short)(r >> 16);
}

__device__ __forceinline__ uint32_t f2u(float f) {
    union { float f; uint32_t u; } v; v.f = f;
    return v.u;
}

__device__ __forceinline__ uint32_t bfround(float f) {
    union { float f; uint32_t u; } v; v.f = f;
    return v.u + 0x7FFFu + ((v.u >> 16) & 1u);
}

// pack 4 f32 -> 4 bf16 (rounded) as uint2
__device__ __forceinline__ uint2 packbf4(f32x4 v) {
    uint32_t r0 = bfround(v[0]), r1 = bfround(v[1]), r2 = bfround(v[2]), r3 = bfround(v[3]);
    uint2 o;
    o.x = __builtin_amdgcn_perm(r1, r0, 0x07060302);
    o.y = __builtin_amdgcn_perm(r3, r2, 0x07060302);
    return o;
}

// tanh-approx gelu (|err| vs erf-gelu < 5e-4)
__device__ __forceinline__ float fast_gelu(float x) {
    const float u = x * (0.79788456f + 0.0356774081f * x * x);
    const float e = EXP2(u * 2.885390082f);          // exp(2u)
    const float t = 1.f - 2.f * RCP(e + 1.f);        // tanh(u)
    return 0.5f * x * (1.f + t);
}

__device__ __forceinline__ void gl2lds16(const void* g, void* lds) {
    __builtin_amdgcn_global_load_lds(
        (const __attribute__((address_space(1))) uint32_t*)g,
        (__attribute__((address_space(3))) uint32_t*)lds,
        16, 0, 0);
}

// ---------------- weight transpose: src f32 [K][N] -> dst bf16 [noff+n][K] ----------------
__global__ void transpose_w(const float* __restrict__ src, unsigned short* __restrict__ dst,
                            int K, int N, long sls, long dls, int noff) {
    src += (long)blockIdx.z * sls;
    dst += (long)blockIdx.z * dls;
    const int k0 = blockIdx.y * 32, n0 = blockIdx.x * 32;
    __shared__ float tile[32][33];
    const int tx = threadIdx.x, ty = threadIdx.y;
#pragma unroll
    for (int i = 0; i < 4; ++i)
        tile[ty*4+i][tx] = src[(long)(k0 + ty*4 + i) * N + n0 + tx];
    __syncthreads();
#pragma unroll
    for (int i = 0; i < 4; ++i)
        dst[(long)(noff + n0 + ty*4 + i) * K + k0 + tx] = f2bf(tile[tx][ty*4+i]);
}

// ---------------- pack qkv biases into [L][2304] f32 ----------------
__global__ void pack_bqkv(const float* __restrict__ bq, const float* __restrict__ bk,
                          const float* __restrict__ bv, float* __restrict__ dst) {
    int i = blockIdx.x * 256 + threadIdx.x;
    if (i >= LY * 2304) return;
    int l = i / 2304, c = i % 2304;
    const float* s = (c < 768) ? bq : (c < 1536 ? bk : bv);
    dst[i] = s[l * 768 + (c % 768)];
}

// ---------------- embedding ----------------
__global__ __launch_bounds__(256) void embed_kernel(const int* __restrict__ idx,
        const float* __restrict__ tok, const float* __restrict__ pos, float* __restrict__ x) {
    const int g = blockIdx.x * 256 + threadIdx.x;
    const int row = g / 192, c = (g % 192) * 4;
    const int t = row & (TT - 1);
    const int tk = idx[row];
    const f32x4 a = *(const f32x4*)(tok + (long)tk * DM + c);
    const f32x4 p = *(const f32x4*)(pos + (long)t * DM + c);
    f32x4 o = a + p;
    *(f32x4*)(x + (long)row * DM + c) = o;
}

// ---------------- layernorm: f32 rows -> bf16, one wave per row ----------------
__global__ __launch_bounds__(256) void ln_kernel(const float* __restrict__ x,
        const float* __restrict__ gg, const float* __restrict__ bb,
        unsigned short* __restrict__ out) {
    const int row = (blockIdx.x * 256 + threadIdx.x) >> 6;
    const int lane = threadIdx.x & 63;
    const float* xr = x + (long)row * DM;
    f32x4 v[3];
#pragma unroll
    for (int i = 0; i < 3; ++i) v[i] = *(const f32x4*)(xr + i * 256 + lane * 4);
    float s = 0.f;
#pragma unroll
    for (int i = 0; i < 3; ++i) s += v[i][0] + v[i][1] + v[i][2] + v[i][3];
#pragma unroll
    for (int m = 1; m < 64; m <<= 1) s += __shfl_xor(s, m);
    const float mu = s * (1.f / 768.f);
    float q = 0.f;
#pragma unroll
    for (int i = 0; i < 3; ++i)
#pragma unroll
        for (int j = 0; j < 4; ++j) { float d = v[i][j] - mu; q += d * d; }
#pragma unroll
    for (int m = 1; m < 64; m <<= 1) q += __shfl_xor(q, m);
    const float rs = rsqrtf(q * (1.f / 768.f) + 1e-5f);
#pragma unroll
    for (int i = 0; i < 3; ++i) {
        const f32x4 g4 = *(const f32x4*)(gg + i * 256 + lane * 4);
        const f32x4 b4 = *(const f32x4*)(bb + i * 256 + lane * 4);
        f32x4 o;
#pragma unroll
        for (int j = 0; j < 4; ++j) o[j] = (v[i][j] - mu) * rs * g4[j] + b4[j];
        *(uint2*)(out + (long)row * DM + i * 256 + lane * 4) = packbf4(o);
    }
}

// ---------------- GEMM: C[M,N] = A[M,K](bf16) @ Bt[N,K]^T(bf16), epilogues ----------------
// Split-K via blockIdx.z (each z does K/gridDim.z of the K loop).
// EP 0: +bias -> bf16 | EP 1: gelu(+bias) -> bf16 | EP 2: res + (+bias) -> f32
// EP 3: plain f32 | EP 4: +bias -> bf16; col>=1536 blocks scatter transposed into vT(aux)
// EP 5: atomic f32 accumulate into Cout (+bias only on z==0, if bias != nullptr)
template <int EP>
__global__ __launch_bounds__(256)
void gemm128(const unsigned short* __restrict__ A, const unsigned short* __restrict__ Bt,
             const float* __restrict__ bias, const float* __restrict__ res,
             void* __restrict__ Cout, int M, int N, int K,
             unsigned short* __restrict__ aux) {
    __shared__ alignas(16) short As[128 * 64];
    __shared__ alignas(16) short Bs[128 * 64];
    const int tid = threadIdx.x;
    const int w = tid >> 6, lane = tid & 63, quad = lane >> 4, r = lane & 15;
    const int wm = w >> 1, wn = w & 1;
    const long rb = (long)blockIdx.x * 128;
    const long cb = (long)blockIdx.y * 128;
    const int ksub = K / (int)gridDim.z;
    const int kbeg = (int)blockIdx.z * ksub;
    const int kend = kbeg + ksub;

    f32x4 acc[4][4];   // [ci][ri]
    const f32x4 z4 = {0.f, 0.f, 0.f, 0.f};
#pragma unroll
    for (int i = 0; i < 4; ++i)
#pragma unroll
        for (int j = 0; j < 4; ++j) acc[i][j] = z4;

    const int lrow = lane >> 3;
    const int lblk = (lane & 7) ^ lrow;   // XOR swizzle (16B blocks)

    for (int k0 = kbeg; k0 < kend; k0 += 64) {
#pragma unroll
        for (int i = 0; i < 4; ++i) {
            const int c = i * 4 + w;
            gl2lds16(A + (rb + 8 * c + lrow) * (long)K + k0 + lblk * 8, (char*)As + c * 1024);
            gl2lds16(Bt + (cb + 8 * c + lrow) * (long)K + k0 + lblk * 8, (char*)Bs + c * 1024);
        }
        __builtin_amdgcn_s_waitcnt(0);
        __syncthreads();
#pragma unroll
        for (int kk = 0; kk < 2; ++kk) {
            bf16x8 af[4], bfr[4];
#pragma unroll
            for (int mi = 0; mi < 4; ++mi) {
                const int row = wm * 64 + mi * 16 + r;
                af[mi] = *(const bf16x8*)((const char*)As + row * 128 + (((kk * 4 + quad) ^ (row & 7)) * 16));
            }
#pragma unroll
            for (int ni = 0; ni < 4; ++ni) {
                const int col = wn * 64 + ni * 16 + r;
                bfr[ni] = *(const bf16x8*)((const char*)Bs + col * 128 + (((kk * 4 + quad) ^ (col & 7)) * 16));
            }
#pragma unroll
            for (int mi = 0; mi < 4; ++mi)
#pragma unroll
                for (int ni = 0; ni < 4; ++ni)
                    acc[ni][mi] = __builtin_amdgcn_mfma_f32_16x16x32_bf16(bfr[ni], af[mi], acc[ni][mi], 0, 0, 0);
        }
        __syncthreads();
    }

    if (EP == 4 && cb >= 1536) {
        // V columns: scatter transposed into vT[(b*NH+h)*64+d][t] (scalar; 1/3 of blocks)
#pragma unroll
        for (int ci = 0; ci < 4; ++ci) {
            const int colb = (int)cb + wn * 64 + ci * 16 + quad * 4;
            const f32x4 b4 = *(const f32x4*)(bias + colb);
            const int c = colb - 1536, hh = c >> 6, dd = c & 63;
#pragma unroll
            for (int ri = 0; ri < 4; ++ri) {
                const int row = (int)rb + wm * 64 + ri * 16 + r;
                const int bb2 = row >> 10, t = row & 1023;
                unsigned short* vbase = aux + (long)((bb2 * NH + hh) * 64 + dd) * TT + t;
#pragma unroll
                for (int reg = 0; reg < 4; ++reg)
                    vbase[(long)reg * TT] = f2bf(acc[ci][ri][reg] + b4[reg]);
            }
        }
        return;
    }

#pragma unroll
    for (int ci = 0; ci < 4; ++ci) {
        const long colb = cb + wn * 64 + ci * 16 + quad * 4;
        f32x4 b4 = z4;
        if (EP == 5) {
            if (bias != nullptr && blockIdx.z == 0) b4 = *(const f32x4*)(bias + colb);
        } else if (EP != 3) {
            b4 = *(const f32x4*)(bias + colb);
        }
#pragma unroll
        for (int ri = 0; ri < 4; ++ri) {
            const long row = rb + wm * 64 + ri * 16 + r;
            const long off = row * (long)N + colb;
            f32x4 v = acc[ci][ri] + b4;
            if (EP == 0 || EP == 4) {
                *(uint2*)((unsigned short*)Cout + off) = packbf4(v);
            } else if (EP == 1) {
#pragma unroll
                for (int j = 0; j < 4; ++j) v[j] = fast_gelu(v[j]);
                *(uint2*)((unsigned short*)Cout + off) = packbf4(v);
            } else if (EP == 2) {
                const f32x4 rr = *(const f32x4*)(res + off);
                *(f32x4*)((float*)Cout + off) = v + rr;
            } else if (EP == 5) {
#pragma unroll
                for (int j = 0; j < 4; ++j)
                    atomicAdd((float*)Cout + off + j, v[j]);
            } else {
                *(f32x4*)((float*)Cout + off) = v;
            }
        }
    }
}

// ---------------- fused causal attention: barrier-free, per-wave strips, direct-global frags --------
#define C1S 0.18033688011112042f  /* 0.125 * log2(e) */

#define LOADK(KT, KF)                                                                     \
    {                                                                                     \
        const unsigned short* kg_ = qkv + (long)(b * TT + (KT) * 32 + r) * 2304           \
                                    + 768 + h * 64 + quad * 8;                            \
        KF[0][0] = *(const bf16x8*)(kg_);                                                 \
        KF[0][1] = *(const bf16x8*)(kg_ + 32);                                            \
        KF[1][0] = *(const bf16x8*)(kg_ + 16 * 2304);                                     \
        KF[1][1] = *(const bf16x8*)(kg_ + 16 * 2304 + 32);                                \
    }

#define PROCESS(KT, KF, KFN)                                                              \
    {                                                                                     \
        const int kt_ = (KT);                                                             \
        const unsigned short* vg_ = vT + (long)(bh * 64 + r) * TT + kt_ * 32 + quad * 8;  \
        bf16x8 vf_[4];                                                                    \
        vf_[0] = *(const bf16x8*)(vg_);                                                   \
        vf_[1] = *(const bf16x8*)(vg_ + 16 * TT);                                         \
        vf_[2] = *(const bf16x8*)(vg_ + 32 * TT);                                         \
        vf_[3] = *(const bf16x8*)(vg_ + 48 * TT);                                         \
        const f32x4 mk0_ = *(const f32x4*)(amask + b * TT + kt_ * 32 + quad * 4);         \
        const f32x4 mk1_ = *(const f32x4*)(amask + b * TT + kt_ * 32 + 16 + quad * 4);    \
        if (kt_ < strip) LOADK(kt_ + 1, KFN);                                             \
        f32x4 st_[2][2];                                                                  \
        _Pragma("unroll")                                                                 \
        for (int qs = 0; qs < 2; ++qs) {                                                  \
            _Pragma("unroll")                                                             \
            for (int nt = 0; nt < 2; ++nt) {                                              \
                st_[qs][nt] = z4;                                                         \
                st_[qs][nt] = __builtin_amdgcn_mfma_f32_16x16x32_bf16(KF[nt][0], qf[qs][0], st_[qs][nt], 0, 0, 0); \
                st_[qs][nt] = __builtin_amdgcn_mfma_f32_16x16x32_bf16(KF[nt][1], qf[qs][1], st_[qs][nt], 0, 0, 0); \
            }                                                                             \
        }                                                                                 \
        f32x4 mb0_, mb1_;                                                                 \
        _Pragma("unroll")                                                                 \
        for (int j = 0; j < 4; ++j) {                                                     \
            mb0_[j] = (mk0_[j] == 0.f) ? NINF : 0.f;                                      \
            mb1_[j] = (mk1_[j] == 0.f) ? NINF : 0.f;                                      \
        }                                                                                 \
        const bool diag_ = (kt_ == strip);                                                \
        _Pragma("unroll")                                                                 \
        for (int qs = 0; qs < 2; ++qs) {                                                  \
            f32x4 t0_, t1_;                                                               \
            _Pragma("unroll")                                                             \
            for (int j = 0; j < 4; ++j) {                                                 \
                t0_[j] = fmaf(st_[qs][0][j], C1S, mb0_[j]);                               \
                t1_[j] = fmaf(st_[qs][1][j], C1S, mb1_[j]);                               \
            }                                                                             \
            if (diag_) {                                                                  \
                const int qg_ = qs * 16 + r;                                              \
                _Pragma("unroll")                                                         \
                for (int j = 0; j < 4; ++j) {                                             \
                    if (quad * 4 + j > qg_)      t0_[j] = NINF;                           \
                    if (16 + quad * 4 + j > qg_) t1_[j] = NINF;                           \
                }                                                                         \
            }                                                                             \
            float mx_ = fmaxf(fmaxf(fmaxf(t0_[0], t0_[1]), fmaxf(t0_[2], t0_[3])),        \
                              fmaxf(fmaxf(t1_[0], t1_[1]), fmaxf(t1_[2], t1_[3])));       \
            mx_ = fmaxf(mx_, __shfl_xor(mx_, 16));                                        \
            mx_ = fmaxf(mx_, __shfl_xor(mx_, 32));                                        \
            const float mnew_ = fmaxf(m_i[qs], mx_);                                      \
            const float alpha_ = EXP2(m_i[qs] - mnew_);                                   \
            m_i[qs] = mnew_;                                                              \
            f32x4 p0_, p1_;                                                               \
            _Pragma("unroll")                                                             \
            for (int j = 0; j < 4; ++j) {                                                 \
                p0_[j] = EXP2(t0_[j] - mnew_);                                            \
                p1_[j] = EXP2(t1_[j] - mnew_);                                            \
            }                                                                             \
            float rs_ = ((p0_[0] + p0_[1]) + (p0_[2] + p0_[3]))                           \
                      + ((p1_[0] + p1_[1]) + (p1_[2] + p1_[3]));                          \
            rs_ += __shfl_xor(rs_, 16);                                                   \
            rs_ += __shfl_xor(rs_, 32);                                                   \
            l_i[qs] = l_i[qs] * alpha_ + rs_;                                             \
            short* Pq_ = Pb + qs * 512;                                                   \
            const uint2 w0_ = { __builtin_amdgcn_perm(f2u(p0_[1]), f2u(p0_[0]), 0x07060302), \
                                __builtin_amdgcn_perm(f2u(p0_[3]), f2u(p0_[2]), 0x07060302) }; \
            const uint2 w1_ = { __builtin_amdgcn_perm(f2u(p1_[1]), f2u(p1_[0]), 0x07060302), \
                                __builtin_amdgcn_perm(f2u(p1_[3]), f2u(p1_[2]), 0x07060302) }; \
            const int half_ = (quad & 1) * 4;                                             \
            *(uint2*)(Pq_ + r * 32 + ((((quad >> 1)) ^ (r & 3)) << 3) + half_) = w0_;     \
            *(uint2*)(Pq_ + r * 32 + (((2 + (quad >> 1)) ^ (r & 3)) << 3) + half_) = w1_; \
            float al_[4];                                                                 \
            _Pragma("unroll")                                                             \
            for (int reg = 0; reg < 4; ++reg)                                             \
                al_[reg] = __shfl(alpha_, (lane & 48) | (quad * 4 + reg));                \
            _Pragma("unroll")                                                             \
            for (int dt = 0; dt < 4; ++dt)                                                \
                _Pragma("unroll")                                                         \
                for (int reg = 0; reg < 4; ++reg) acc[qs][dt][reg] *= al_[reg];           \
            const bf16x8 pf_ = *(const bf16x8*)(Pq_ + r * 32 + ((quad ^ (r & 3)) << 3));  \
            _Pragma("unroll")                                                             \
            for (int dt = 0; dt < 4; ++dt)                                                \
                acc[qs][dt] = __builtin_amdgcn_mfma_f32_16x16x32_bf16(pf_, vf_[dt], acc[qs][dt], 0, 0, 0); \
        }                                                                                 \
    }

__global__ __launch_bounds__(256, 3)
void attn_kernel(const unsigned short* __restrict__ qkv, const unsigned short* __restrict__ vT,
                 const float* __restrict__ amask, unsigned short* __restrict__ y) {
    const int bh = blockIdx.x, b = bh / NH, h = bh % NH;
    const int tid = threadIdx.x, w = tid >> 6, lane = tid & 63, quad = lane >> 4, r = lane & 15;
    const int strip = w * 8 + blockIdx.y;   // 0..31
    const int q0 = strip * 32;

    __shared__ alignas(16) short Pall[4 * 2 * 512];
    short* Pb = Pall + w * 1024;

    const float NINF = -__builtin_inff();
    const f32x4 z4 = {0.f, 0.f, 0.f, 0.f};

    bf16x8 qf[2][2];
#pragma unroll
    for (int qs = 0; qs < 2; ++qs)
#pragma unroll
        for (int ks = 0; ks < 2; ++ks)
            qf[qs][ks] = *(const bf16x8*)(qkv + (long)(b * TT + q0 + qs * 16 + r) * 2304
                                          + h * 64 + ks * 32 + quad * 8);

    f32x4 acc[2][4];
    float m_i[2] = {NINF, NINF}, l_i[2] = {0.f, 0.f};
#pragma unroll
    for (int qs = 0; qs < 2; ++qs)
#pragma unroll
        for (int dt = 0; dt < 4; ++dt) acc[qs][dt] = z4;

    bf16x8 kfA[2][2], kfB[2][2];
    LOADK(0, kfA);
    int kt = 0;
    for (;;) {
        PROCESS(kt, kfA, kfB);
        ++kt; if (kt > strip) break;
        PROCESS(kt, kfB, kfA);
        ++kt; if (kt > strip) break;
    }

#pragma unroll
    for (int qs = 0; qs < 2; ++qs) {
        const float inv0 = 1.0f / l_i[qs];
#pragma unroll
        for (int reg = 0; reg < 4; ++reg) {
            const float inv = __shfl(inv0, (lane & 48) | (quad * 4 + reg));
            const long row = b * TT + q0 + qs * 16 + quad * 4 + reg;
#pragma unroll
            for (int dt = 0; dt < 4; ++dt)
                y[row * DM + h * 64 + dt * 16 + r] = f2bf(acc[qs][dt][reg] * inv);
        }
    }
}

// ---------------- host ----------------
extern "C" void kernel_launch(void* const* d_in, const int* in_sizes, int n_in,
                              void* d_out, int out_size, void* d_ws, size_t ws_size,
                              hipStream_t stream) {
    (void)in_sizes; (void)n_in; (void)out_size; (void)ws_size;
    const int*   idx   = (const int*)d_in[0];
    const float* amask = (const float*)d_in[1];
    const float* tok   = (const float*)d_in[2];
    const float* pos   = (const float*)d_in[3];
    const float* ln1g  = (const float*)d_in[4];
    const float* ln1b  = (const float*)d_in[5];
    const float* Wq    = (const float*)d_in[6];
    const float* bq    = (const float*)d_in[7];
    const float* Wk    = (const float*)d_in[8];
    const float* bk    = (const float*)d_in[9];
    const float* Wv    = (const float*)d_in[10];
    const float* bv    = (const float*)d_in[11];
    const float* Wo    = (const float*)d_in[12];
    const float* bo    = (const float*)d_in[13];
    const float* ln2g  = (const float*)d_in[14];
    const float* ln2b  = (const float*)d_in[15];
    const float* W1    = (const float*)d_in[16];
    const float* b1    = (const float*)d_in[17];
    const float* W2    = (const float*)d_in[18];
    const float* b2    = (const float*)d_in[19];
    const float* lnfg  = (const float*)d_in[20];
    const float* lnfb  = (const float*)d_in[21];
    const float* Wout  = (const float*)d_in[22];

    char* ws = (char*)d_ws;
    float* x            = (float*)ws;          ws += (size_t)ROWS * DM * 4;
    unsigned short* h   = (unsigned short*)ws; ws += (size_t)ROWS * DM * 2;
    unsigned short* qkv = (unsigned short*)ws; ws += (size_t)ROWS * 2304 * 2;
    unsigned short* vT  = (unsigned short*)ws; ws += (size_t)ROWS * DM * 2;
    unsigned short* y   = (unsigned short*)ws; ws += (size_t)ROWS * DM * 2;
    unsigned short* m1  = (unsigned short*)ws; ws += (size_t)ROWS * FFD * 2;
    unsigned short* qkvT= (unsigned short*)ws; ws += (size_t)LY * 2304 * DM * 2;
    unsigned short* WoT = (unsigned short*)ws; ws += (size_t)LY * DM * DM * 2;
    unsigned short* W1T = (unsigned short*)ws; ws += (size_t)LY * FFD * DM * 2;
    unsigned short* W2T = (unsigned short*)ws; ws += (size_t)LY * DM * FFD * 2;
    unsigned short* WouT= (unsigned short*)ws; ws += (size_t)VOC * DM * 2;
    float* bqkv         = (float*)ws;          ws += (size_t)LY * 2304 * 4;

    dim3 blk32(32, 8, 1);
    transpose_w<<<dim3(24, 24, LY), blk32, 0, stream>>>(Wq, qkvT, 768, 768, 768L*768, 2304L*768, 0);
    transpose_w<<<dim3(24, 24, LY), blk32, 0, stream>>>(Wk, qkvT, 768, 768, 768L*768, 2304L*768, 768);
    transpose_w<<<dim3(24, 24, LY), blk32, 0, stream>>>(Wv, qkvT, 768, 768, 768L*768, 2304L*768, 1536);
    transpose_w<<<dim3(24, 24, LY), blk32, 0, stream>>>(Wo, WoT, 768, 768, 768L*768, 768L*768, 0);
    transpose_w<<<dim3(96, 24, LY), blk32, 0, stream>>>(W1, W1T, 768, 3072, 768L*3072, 3072L*768, 0);
    transpose_w<<<dim3(24, 96, LY), blk32, 0, stream>>>(W2, W2T, 3072, 768, 3072L*768, 768L*3072, 0);
    transpose_w<<<dim3(16, 24, 1),  blk32, 0, stream>>>(Wout, WouT, 768, 512, 768L*512, 512L*768, 0);
    pack_bqkv<<<dim3(54), 256, 0, stream>>>(bq, bk, bv, bqkv);
    embed_kernel<<<dim3(6144), 256, 0, stream>>>(idx, tok, pos, x);

    for (int l = 0; l < LY; ++l) {
        ln_kernel<<<2048, 256, 0, stream>>>(x, ln1g + l * DM, ln1b + l * DM, h);
        gemm128<4><<<dim3(64, 18), 256, 0, stream>>>(h, qkvT + (size_t)l * 2304 * DM, bqkv + l * 2304,
                                                     nullptr, qkv, ROWS, 2304, DM, vT);
        attn_kernel<<<dim3(96, 8), 256, 0, stream>>>(qkv, vT, amask, y);
        gemm128<5><<<dim3(64, 6, 2), 256, 0, stream>>>(y, WoT + (size_t)l * DM * DM, bo + l * DM,
                                                       nullptr, x, ROWS, DM, DM, nullptr);
        ln_kernel<<<2048, 256, 0, stream>>>(x, ln2g + l * DM, ln2b + l * DM, h);
        gemm128<1><<<dim3(64, 24), 256, 0, stream>>>(h, W1T + (size_t)l * FFD * DM, b1 + l * FFD,
                                                     nullptr, m1, ROWS, FFD, DM, nullptr);
        gemm128<5><<<dim3(64, 6, 2), 256, 0, stream>>>(m1, W2T + (size_t)l * DM * FFD, b2 + l * DM,
                                                       nullptr, x, ROWS, DM, FFD, nullptr);
    }
    ln_kernel<<<2048, 256, 0, stream>>>(x, lnfg, lnfb, h);
    hipMemsetAsync(d_out, 0, (size_t)ROWS * VOC * 4, stream);
    gemm128<5><<<dim3(64, 4, 2), 256, 0, stream>>>(h, WouT, nullptr, nullptr, d_out, ROWS, VOC, DM, nullptr);
}

// Round 6
// 1806.232 us; speedup vs baseline: 1.9407x; 1.9407x over previous
//
#include <hip/hip_runtime.h>
#include <stdint.h>

#define LY 6
#define VOC 512
#define DM 768
#define NH 12
#define HD 64
#define FFD 3072
#define BB 8
#define TT 1024
#define ROWS (BB*TT)

typedef short bf16x8 __attribute__((ext_vector_type(8)));
typedef float f32x4 __attribute__((ext_vector_type(4)));
typedef unsigned short u16x4 __attribute__((ext_vector_type(4)));

#if __has_builtin(__builtin_amdgcn_exp2f)
#define EXP2 __builtin_amdgcn_exp2f
#else
#define EXP2 exp2f
#endif

#if __has_builtin(__builtin_amdgcn_rcpf)
#define RCP __builtin_amdgcn_rcpf
#else
#define RCP(x) (1.0f/(x))
#endif

__device__ __forceinline__ unsigned short f2bf(float f) {
    union { float f; uint32_t u; } v; v.f = f;
    uint32_t r = v.u + 0x7FFFu + ((v.u >> 16) & 1u);
    return (unsigned short)(r >> 16);
}

__device__ __forceinline__ uint32_t f2u(float f) {
    union { float f; uint32_t u; } v; v.f = f;
    return v.u;
}

__device__ __forceinline__ uint32_t bfround(float f) {
    union { float f; uint32_t u; } v; v.f = f;
    return v.u + 0x7FFFu + ((v.u >> 16) & 1u);
}

// pack 4 f32 -> 4 bf16 (rounded) as uint2
__device__ __forceinline__ uint2 packbf4(f32x4 v) {
    uint32_t r0 = bfround(v[0]), r1 = bfround(v[1]), r2 = bfround(v[2]), r3 = bfround(v[3]);
    uint2 o;
    o.x = __builtin_amdgcn_perm(r1, r0, 0x07060302);
    o.y = __builtin_amdgcn_perm(r3, r2, 0x07060302);
    return o;
}

// tanh-approx gelu (|err| vs erf-gelu < 5e-4)
__device__ __forceinline__ float fast_gelu(float x) {
    const float u = x * (0.79788456f + 0.0356774081f * x * x);
    const float e = EXP2(u * 2.885390082f);          // exp(2u)
    const float t = 1.f - 2.f * RCP(e + 1.f);        // tanh(u)
    return 0.5f * x * (1.f + t);
}

__device__ __forceinline__ void gl2lds16(const void* g, void* lds) {
    __builtin_amdgcn_global_load_lds(
        (const __attribute__((address_space(1))) uint32_t*)g,
        (__attribute__((address_space(3))) uint32_t*)lds,
        16, 0, 0);
}

// ---------------- weight transpose: src f32 [K][N] -> dst bf16 [noff+n][K] ----------------
__global__ void transpose_w(const float* __restrict__ src, unsigned short* __restrict__ dst,
                            int K, int N, long sls, long dls, int noff) {
    src += (long)blockIdx.z * sls;
    dst += (long)blockIdx.z * dls;
    const int k0 = blockIdx.y * 32, n0 = blockIdx.x * 32;
    __shared__ float tile[32][33];
    const int tx = threadIdx.x, ty = threadIdx.y;
#pragma unroll
    for (int i = 0; i < 4; ++i)
        tile[ty*4+i][tx] = src[(long)(k0 + ty*4 + i) * N + n0 + tx];
    __syncthreads();
#pragma unroll
    for (int i = 0; i < 4; ++i)
        dst[(long)(noff + n0 + ty*4 + i) * K + k0 + tx] = f2bf(tile[tx][ty*4+i]);
}

// ---------------- pack qkv biases into [L][2304] f32 ----------------
__global__ void pack_bqkv(const float* __restrict__ bq, const float* __restrict__ bk,
                          const float* __restrict__ bv, float* __restrict__ dst) {
    int i = blockIdx.x * 256 + threadIdx.x;
    if (i >= LY * 2304) return;
    int l = i / 2304, c = i % 2304;
    const float* s = (c < 768) ? bq : (c < 1536 ? bk : bv);
    dst[i] = s[l * 768 + (c % 768)];
}

// ---------------- embedding ----------------
__global__ __launch_bounds__(256) void embed_kernel(const int* __restrict__ idx,
        const float* __restrict__ tok, const float* __restrict__ pos, float* __restrict__ x) {
    const int g = blockIdx.x * 256 + threadIdx.x;
    const int row = g / 192, c = (g % 192) * 4;
    const int t = row & (TT - 1);
    const int tk = idx[row];
    const f32x4 a = *(const f32x4*)(tok + (long)tk * DM + c);
    const f32x4 p = *(const f32x4*)(pos + (long)t * DM + c);
    f32x4 o = a + p;
    *(f32x4*)(x + (long)row * DM + c) = o;
}

// ---------------- layernorm: f32 rows -> bf16, one wave per row ----------------
__global__ __launch_bounds__(256) void ln_kernel(const float* __restrict__ x,
        const float* __restrict__ gg, const float* __restrict__ bb,
        unsigned short* __restrict__ out) {
    const int row = (blockIdx.x * 256 + threadIdx.x) >> 6;
    const int lane = threadIdx.x & 63;
    const float* xr = x + (long)row * DM;
    f32x4 v[3];
#pragma unroll
    for (int i = 0; i < 3; ++i) v[i] = *(const f32x4*)(xr + i * 256 + lane * 4);
    float s = 0.f;
#pragma unroll
    for (int i = 0; i < 3; ++i) s += v[i][0] + v[i][1] + v[i][2] + v[i][3];
#pragma unroll
    for (int m = 1; m < 64; m <<= 1) s += __shfl_xor(s, m);
    const float mu = s * (1.f / 768.f);
    float q = 0.f;
#pragma unroll
    for (int i = 0; i < 3; ++i)
#pragma unroll
        for (int j = 0; j < 4; ++j) { float d = v[i][j] - mu; q += d * d; }
#pragma unroll
    for (int m = 1; m < 64; m <<= 1) q += __shfl_xor(q, m);
    const float rs = rsqrtf(q * (1.f / 768.f) + 1e-5f);
#pragma unroll
    for (int i = 0; i < 3; ++i) {
        const f32x4 g4 = *(const f32x4*)(gg + i * 256 + lane * 4);
        const f32x4 b4 = *(const f32x4*)(bb + i * 256 + lane * 4);
        f32x4 o;
#pragma unroll
        for (int j = 0; j < 4; ++j) o[j] = (v[i][j] - mu) * rs * g4[j] + b4[j];
        *(uint2*)(out + (long)row * DM + i * 256 + lane * 4) = packbf4(o);
    }
}

// ---------------- GEMM: C[M,N] = A[M,K](bf16) @ Bt[N,K]^T(bf16), epilogues ----------------
// BN = 128: 4 waves in 2x2, each 64x64.  BN = 64: 4 waves in 4x1, each 32x64 (768-block grids).
// EP 0: +bias -> bf16 | EP 1: gelu(+bias) -> bf16 | EP 2: res + (+bias) -> f32
// EP 3: plain f32 | EP 4: +bias -> bf16; col>=1536 blocks scatter transposed into vT(aux)
template <int EP, int BN>
__global__ __launch_bounds__(256)
void gemm128(const unsigned short* __restrict__ A, const unsigned short* __restrict__ Bt,
             const float* __restrict__ bias, const float* __restrict__ res,
             void* __restrict__ Cout, int M, int N, int K,
             unsigned short* __restrict__ aux) {
    constexpr int MI = (BN == 128) ? 4 : 2;   // 16-row tiles per wave
    __shared__ alignas(16) short As[128 * 64];
    __shared__ alignas(16) short Bs[BN * 64];
    const int tid = threadIdx.x;
    const int w = tid >> 6, lane = tid & 63, quad = lane >> 4, r = lane & 15;
    const int wm = (BN == 128) ? (w >> 1) : w;
    const int wn = (BN == 128) ? (w & 1) : 0;
    const long rb = (long)blockIdx.x * 128;
    const long cb = (long)blockIdx.y * BN;

    f32x4 acc[4][MI];   // [ci][ri]
    const f32x4 z4 = {0.f, 0.f, 0.f, 0.f};
#pragma unroll
    for (int i = 0; i < 4; ++i)
#pragma unroll
        for (int j = 0; j < MI; ++j) acc[i][j] = z4;

    const int lrow = lane >> 3;
    const int lblk = (lane & 7) ^ lrow;   // XOR swizzle (16B blocks)

    for (int k0 = 0; k0 < K; k0 += 64) {
#pragma unroll
        for (int i = 0; i < 4; ++i) {
            const int c = i * 4 + w;
            gl2lds16(A + (rb + 8 * c + lrow) * (long)K + k0 + lblk * 8, (char*)As + c * 1024);
        }
#pragma unroll
        for (int i = 0; i < BN / 32; ++i) {
            const int c = i * 4 + w;
            gl2lds16(Bt + (cb + 8 * c + lrow) * (long)K + k0 + lblk * 8, (char*)Bs + c * 1024);
        }
        __builtin_amdgcn_s_waitcnt(0);
        __syncthreads();
#pragma unroll
        for (int kk = 0; kk < 2; ++kk) {
            bf16x8 af[MI], bfr[4];
#pragma unroll
            for (int mi = 0; mi < MI; ++mi) {
                const int row = wm * (MI * 16) + mi * 16 + r;
                af[mi] = *(const bf16x8*)((const char*)As + row * 128 + (((kk * 4 + quad) ^ (row & 7)) * 16));
            }
#pragma unroll
            for (int ni = 0; ni < 4; ++ni) {
                const int col = wn * 64 + ni * 16 + r;
                bfr[ni] = *(const bf16x8*)((const char*)Bs + col * 128 + (((kk * 4 + quad) ^ (col & 7)) * 16));
            }
#pragma unroll
            for (int mi = 0; mi < MI; ++mi)
#pragma unroll
                for (int ni = 0; ni < 4; ++ni)
                    acc[ni][mi] = __builtin_amdgcn_mfma_f32_16x16x32_bf16(bfr[ni], af[mi], acc[ni][mi], 0, 0, 0);
        }
        __syncthreads();
    }

    if (EP == 4 && cb >= 1536) {
        // V columns: scatter transposed into vT[(b*NH+h)*64+d][t] (scalar; 1/3 of blocks)
#pragma unroll
        for (int ci = 0; ci < 4; ++ci) {
            const int colb = (int)cb + wn * 64 + ci * 16 + quad * 4;
            const f32x4 b4 = *(const f32x4*)(bias + colb);
            const int c = colb - 1536, hh = c >> 6, dd = c & 63;
#pragma unroll
            for (int ri = 0; ri < MI; ++ri) {
                const int row = (int)rb + wm * (MI * 16) + ri * 16 + r;
                const int bb2 = row >> 10, t = row & 1023;
                unsigned short* vbase = aux + (long)((bb2 * NH + hh) * 64 + dd) * TT + t;
#pragma unroll
                for (int reg = 0; reg < 4; ++reg)
                    vbase[(long)reg * TT] = f2bf(acc[ci][ri][reg] + b4[reg]);
            }
        }
        return;
    }

#pragma unroll
    for (int ci = 0; ci < 4; ++ci) {
        const long colb = cb + wn * 64 + ci * 16 + quad * 4;
        f32x4 b4 = z4;
        if (EP != 3) b4 = *(const f32x4*)(bias + colb);
#pragma unroll
        for (int ri = 0; ri < MI; ++ri) {
            const long row = rb + wm * (MI * 16) + ri * 16 + r;
            const long off = row * (long)N + colb;
            f32x4 v = acc[ci][ri] + b4;
            if (EP == 0 || EP == 4) {
                *(uint2*)((unsigned short*)Cout + off) = packbf4(v);
            } else if (EP == 1) {
#pragma unroll
                for (int j = 0; j < 4; ++j) v[j] = fast_gelu(v[j]);
                *(uint2*)((unsigned short*)Cout + off) = packbf4(v);
            } else if (EP == 2) {
                const f32x4 rr = *(const f32x4*)(res + off);
                *(f32x4*)((float*)Cout + off) = v + rr;
            } else {
                *(f32x4*)((float*)Cout + off) = v;
            }
        }
    }
}

// ---------------- fused causal attention: barrier-free, per-wave strips, direct-global frags --------
#define C1S 0.18033688011112042f  /* 0.125 * log2(e) */

#define LOADK(KT, KF)                                                                     \
    {                                                                                     \
        const unsigned short* kg_ = qkv + (long)(b * TT + (KT) * 32 + r) * 2304           \
                                    + 768 + h * 64 + quad * 8;                            \
        KF[0][0] = *(const bf16x8*)(kg_);                                                 \
        KF[0][1] = *(const bf16x8*)(kg_ + 32);                                            \
        KF[1][0] = *(const bf16x8*)(kg_ + 16 * 2304);                                     \
        KF[1][1] = *(const bf16x8*)(kg_ + 16 * 2304 + 32);                                \
    }

#define PROCESS(KT, KF, KFN)                                                              \
    {                                                                                     \
        const int kt_ = (KT);                                                             \
        const unsigned short* vg_ = vT + (long)(bh * 64 + r) * TT + kt_ * 32 + quad * 8;  \
        bf16x8 vf_[4];                                                                    \
        vf_[0] = *(const bf16x8*)(vg_);                                                   \
        vf_[1] = *(const bf16x8*)(vg_ + 16 * TT);                                         \
        vf_[2] = *(const bf16x8*)(vg_ + 32 * TT);                                         \
        vf_[3] = *(const bf16x8*)(vg_ + 48 * TT);                                         \
        const f32x4 mk0_ = *(const f32x4*)(amask + b * TT + kt_ * 32 + quad * 4);         \
        const f32x4 mk1_ = *(const f32x4*)(amask + b * TT + kt_ * 32 + 16 + quad * 4);    \
        if (kt_ < strip) LOADK(kt_ + 1, KFN);                                             \
        f32x4 st_[2][2];                                                                  \
        _Pragma("unroll")                                                                 \
        for (int qs = 0; qs < 2; ++qs) {                                                  \
            _Pragma("unroll")                                                             \
            for (int nt = 0; nt < 2; ++nt) {                                              \
                st_[qs][nt] = z4;                                                         \
                st_[qs][nt] = __builtin_amdgcn_mfma_f32_16x16x32_bf16(KF[nt][0], qf[qs][0], st_[qs][nt], 0, 0, 0); \
                st_[qs][nt] = __builtin_amdgcn_mfma_f32_16x16x32_bf16(KF[nt][1], qf[qs][1], st_[qs][nt], 0, 0, 0); \
            }                                                                             \
        }                                                                                 \
        f32x4 mb0_, mb1_;                                                                 \
        _Pragma("unroll")                                                                 \
        for (int j = 0; j < 4; ++j) {                                                     \
            mb0_[j] = (mk0_[j] == 0.f) ? NINF : 0.f;                                      \
            mb1_[j] = (mk1_[j] == 0.f) ? NINF : 0.f;                                      \
        }                                                                                 \
        const bool diag_ = (kt_ == strip);                                                \
        _Pragma("unroll")                                                                 \
        for (int qs = 0; qs < 2; ++qs) {                                                  \
            f32x4 t0_, t1_;                                                               \
            _Pragma("unroll")                                                             \
            for (int j = 0; j < 4; ++j) {                                                 \
                t0_[j] = fmaf(st_[qs][0][j], C1S, mb0_[j]);                               \
                t1_[j] = fmaf(st_[qs][1][j], C1S, mb1_[j]);                               \
            }                                                                             \
            if (diag_) {                                                                  \
                const int qg_ = qs * 16 + r;                                              \
                _Pragma("unroll")                                                         \
                for (int j = 0; j < 4; ++j) {                                             \
                    if (quad * 4 + j > qg_)      t0_[j] = NINF;                           \
                    if (16 + quad * 4 + j > qg_) t1_[j] = NINF;                           \
                }                                                                         \
            }                                                                             \
            float mx_ = fmaxf(fmaxf(fmaxf(t0_[0], t0_[1]), fmaxf(t0_[2], t0_[3])),        \
                              fmaxf(fmaxf(t1_[0], t1_[1]), fmaxf(t1_[2], t1_[3])));       \
            mx_ = fmaxf(mx_, __shfl_xor(mx_, 16));                                        \
            mx_ = fmaxf(mx_, __shfl_xor(mx_, 32));                                        \
            const float mnew_ = fmaxf(m_i[qs], mx_);                                      \
            const float alpha_ = EXP2(m_i[qs] - mnew_);                                   \
            m_i[qs] = mnew_;                                                              \
            f32x4 p0_, p1_;                                                               \
            _Pragma("unroll")                                                             \
            for (int j = 0; j < 4; ++j) {                                                 \
                p0_[j] = EXP2(t0_[j] - mnew_);                                            \
                p1_[j] = EXP2(t1_[j] - mnew_);                                            \
            }                                                                             \
            float rs_ = ((p0_[0] + p0_[1]) + (p0_[2] + p0_[3]))                           \
                      + ((p1_[0] + p1_[1]) + (p1_[2] + p1_[3]));                          \
            rs_ += __shfl_xor(rs_, 16);                                                   \
            rs_ += __shfl_xor(rs_, 32);                                                   \
            l_i[qs] = l_i[qs] * alpha_ + rs_;                                             \
            short* Pq_ = Pb + qs * 512;                                                   \
            const uint2 w0_ = { __builtin_amdgcn_perm(f2u(p0_[1]), f2u(p0_[0]), 0x07060302), \
                                __builtin_amdgcn_perm(f2u(p0_[3]), f2u(p0_[2]), 0x07060302) }; \
            const uint2 w1_ = { __builtin_amdgcn_perm(f2u(p1_[1]), f2u(p1_[0]), 0x07060302), \
                                __builtin_amdgcn_perm(f2u(p1_[3]), f2u(p1_[2]), 0x07060302) }; \
            const int half_ = (quad & 1) * 4;                                             \
            *(uint2*)(Pq_ + r * 32 + ((((quad >> 1)) ^ (r & 3)) << 3) + half_) = w0_;     \
            *(uint2*)(Pq_ + r * 32 + (((2 + (quad >> 1)) ^ (r & 3)) << 3) + half_) = w1_; \
            float al_[4];                                                                 \
            _Pragma("unroll")                                                             \
            for (int reg = 0; reg < 4; ++reg)                                             \
                al_[reg] = __shfl(alpha_, (lane & 48) | (quad * 4 + reg));                \
            _Pragma("unroll")                                                             \
            for (int dt = 0; dt < 4; ++dt)                                                \
                _Pragma("unroll")                                                         \
                for (int reg = 0; reg < 4; ++reg) acc[qs][dt][reg] *= al_[reg];           \
            const bf16x8 pf_ = *(const bf16x8*)(Pq_ + r * 32 + ((quad ^ (r & 3)) << 3));  \
            _Pragma("unroll")                                                             \
            for (int dt = 0; dt < 4; ++dt)                                                \
                acc[qs][dt] = __builtin_amdgcn_mfma_f32_16x16x32_bf16(pf_, vf_[dt], acc[qs][dt], 0, 0, 0); \
        }                                                                                 \
    }

__global__ __launch_bounds__(256, 3)
void attn_kernel(const unsigned short* __restrict__ qkv, const unsigned short* __restrict__ vT,
                 const float* __restrict__ amask, unsigned short* __restrict__ y) {
    const int bh = blockIdx.x, b = bh / NH, h = bh % NH;
    const int tid = threadIdx.x, w = tid >> 6, lane = tid & 63, quad = lane >> 4, r = lane & 15;
    const int strip = w * 8 + blockIdx.y;   // 0..31
    const int q0 = strip * 32;

    __shared__ alignas(16) short Pall[4 * 2 * 512];
    short* Pb = Pall + w * 1024;

    const float NINF = -__builtin_inff();
    const f32x4 z4 = {0.f, 0.f, 0.f, 0.f};

    bf16x8 qf[2][2];
#pragma unroll
    for (int qs = 0; qs < 2; ++qs)
#pragma unroll
        for (int ks = 0; ks < 2; ++ks)
            qf[qs][ks] = *(const bf16x8*)(qkv + (long)(b * TT + q0 + qs * 16 + r) * 2304
                                          + h * 64 + ks * 32 + quad * 8);

    f32x4 acc[2][4];
    float m_i[2] = {NINF, NINF}, l_i[2] = {0.f, 0.f};
#pragma unroll
    for (int qs = 0; qs < 2; ++qs)
#pragma unroll
        for (int dt = 0; dt < 4; ++dt) acc[qs][dt] = z4;

    bf16x8 kfA[2][2], kfB[2][2];
    LOADK(0, kfA);
    int kt = 0;
    for (;;) {
        PROCESS(kt, kfA, kfB);
        ++kt; if (kt > strip) break;
        PROCESS(kt, kfB, kfA);
        ++kt; if (kt > strip) break;
    }

#pragma unroll
    for (int qs = 0; qs < 2; ++qs) {
        const float inv0 = 1.0f / l_i[qs];
#pragma unroll
        for (int reg = 0; reg < 4; ++reg) {
            const float inv = __shfl(inv0, (lane & 48) | (quad * 4 + reg));
            const long row = b * TT + q0 + qs * 16 + quad * 4 + reg;
#pragma unroll
            for (int dt = 0; dt < 4; ++dt)
                y[row * DM + h * 64 + dt * 16 + r] = f2bf(acc[qs][dt][reg] * inv);
        }
    }
}

// ---------------- host ----------------
extern "C" void kernel_launch(void* const* d_in, const int* in_sizes, int n_in,
                              void* d_out, int out_size, void* d_ws, size_t ws_size,
                              hipStream_t stream) {
    (void)in_sizes; (void)n_in; (void)out_size; (void)ws_size;
    const int*   idx   = (const int*)d_in[0];
    const float* amask = (const float*)d_in[1];
    const float* tok   = (const float*)d_in[2];
    const float* pos   = (const float*)d_in[3];
    const float* ln1g  = (const float*)d_in[4];
    const float* ln1b  = (const float*)d_in[5];
    const float* Wq    = (const float*)d_in[6];
    const float* bq    = (const float*)d_in[7];
    const float* Wk    = (const float*)d_in[8];
    const float* bk    = (const float*)d_in[9];
    const float* Wv    = (const float*)d_in[10];
    const float* bv    = (const float*)d_in[11];
    const float* Wo    = (const float*)d_in[12];
    const float* bo    = (const float*)d_in[13];
    const float* ln2g  = (const float*)d_in[14];
    const float* ln2b  = (const float*)d_in[15];
    const float* W1    = (const float*)d_in[16];
    const float* b1    = (const float*)d_in[17];
    const float* W2    = (const float*)d_in[18];
    const float* b2    = (const float*)d_in[19];
    const float* lnfg  = (const float*)d_in[20];
    const float* lnfb  = (const float*)d_in[21];
    const float* Wout  = (const float*)d_in[22];

    char* ws = (char*)d_ws;
    float* x            = (float*)ws;          ws += (size_t)ROWS * DM * 4;
    unsigned short* h   = (unsigned short*)ws; ws += (size_t)ROWS * DM * 2;
    unsigned short* qkv = (unsigned short*)ws; ws += (size_t)ROWS * 2304 * 2;
    unsigned short* vT  = (unsigned short*)ws; ws += (size_t)ROWS * DM * 2;
    unsigned short* y   = (unsigned short*)ws; ws += (size_t)ROWS * DM * 2;
    unsigned short* m1  = (unsigned short*)ws; ws += (size_t)ROWS * FFD * 2;
    unsigned short* qkvT= (unsigned short*)ws; ws += (size_t)LY * 2304 * DM * 2;
    unsigned short* WoT = (unsigned short*)ws; ws += (size_t)LY * DM * DM * 2;
    unsigned short* W1T = (unsigned short*)ws; ws += (size_t)LY * FFD * DM * 2;
    unsigned short* W2T = (unsigned short*)ws; ws += (size_t)LY * DM * FFD * 2;
    unsigned short* WouT= (unsigned short*)ws; ws += (size_t)VOC * DM * 2;
    float* bqkv         = (float*)ws;          ws += (size_t)LY * 2304 * 4;

    dim3 blk32(32, 8, 1);
    transpose_w<<<dim3(24, 24, LY), blk32, 0, stream>>>(Wq, qkvT, 768, 768, 768L*768, 2304L*768, 0);
    transpose_w<<<dim3(24, 24, LY), blk32, 0, stream>>>(Wk, qkvT, 768, 768, 768L*768, 2304L*768, 768);
    transpose_w<<<dim3(24, 24, LY), blk32, 0, stream>>>(Wv, qkvT, 768, 768, 768L*768, 2304L*768, 1536);
    transpose_w<<<dim3(24, 24, LY), blk32, 0, stream>>>(Wo, WoT, 768, 768, 768L*768, 768L*768, 0);
    transpose_w<<<dim3(96, 24, LY), blk32, 0, stream>>>(W1, W1T, 768, 3072, 768L*3072, 3072L*768, 0);
    transpose_w<<<dim3(24, 96, LY), blk32, 0, stream>>>(W2, W2T, 3072, 768, 3072L*768, 768L*3072, 0);
    transpose_w<<<dim3(16, 24, 1),  blk32, 0, stream>>>(Wout, WouT, 768, 512, 768L*512, 512L*768, 0);
    pack_bqkv<<<dim3(54), 256, 0, stream>>>(bq, bk, bv, bqkv);
    embed_kernel<<<dim3(6144), 256, 0, stream>>>(idx, tok, pos, x);

    for (int l = 0; l < LY; ++l) {
        ln_kernel<<<2048, 256, 0, stream>>>(x, ln1g + l * DM, ln1b + l * DM, h);
        gemm128<4,128><<<dim3(64, 18), 256, 0, stream>>>(h, qkvT + (size_t)l * 2304 * DM, bqkv + l * 2304,
                                                         nullptr, qkv, ROWS, 2304, DM, vT);
        attn_kernel<<<dim3(96, 8), 256, 0, stream>>>(qkv, vT, amask, y);
        gemm128<2,64><<<dim3(64, 12), 256, 0, stream>>>(y, WoT + (size_t)l * DM * DM, bo + l * DM,
                                                        x, x, ROWS, DM, DM, nullptr);
        ln_kernel<<<2048, 256, 0, stream>>>(x, ln2g + l * DM, ln2b + l * DM, h);
        gemm128<1,128><<<dim3(64, 24), 256, 0, stream>>>(h, W1T + (size_t)l * FFD * DM, b1 + l * FFD,
                                                         nullptr, m1, ROWS, FFD, DM, nullptr);
        gemm128<2,64><<<dim3(64, 12), 256, 0, stream>>>(m1, W2T + (size_t)l * DM * FFD, b2 + l * DM,
                                                        x, x, ROWS, DM, FFD, nullptr);
    }
    ln_kernel<<<2048, 256, 0, stream>>>(x, lnfg, lnfb, h);
    gemm128<3,64><<<dim3(64, 8), 256, 0, stream>>>(h, WouT, nullptr, nullptr, d_out, ROWS, VOC, DM, nullptr);
}